// Round 13
// baseline (219.885 us; speedup 1.0000x reference)
//
#include <hip/hip_runtime.h>
#include <hip/hip_bf16.h>

#define TSEQ 2048
#define NHEAD 16
#define DM 1024
#define NBATCH 2
#define MTOK (NBATCH * TSEQ)   // 4096

typedef __attribute__((ext_vector_type(8))) short short8;
typedef __attribute__((ext_vector_type(4))) float floatx4;
typedef __attribute__((address_space(1))) const void gvoid;
typedef __attribute__((address_space(3))) void lvoid;

static __device__ __forceinline__ unsigned short f2bf(float f) {
    unsigned int u = __float_as_uint(f);
    return (unsigned short)((u + 0x7fffu + ((u >> 16) & 1u)) >> 16);
}
static __device__ __forceinline__ float bf2f(unsigned short h) {
    return __uint_as_float(((unsigned int)h) << 16);
}

// ---------------------------------------------------------------------------
// Pack x and the 6 weight matrices to bf16 rows (single precision level).
//   x, Wproj, Wq..Wv -> [hi(1024) | dead]
//   Wq,Wk,Wq2,Wk2 rows additionally PER-HEAD INTERLEAVED:
//     d<32 -> (d>>3)*16 + (d&7) ; d>=32 -> ((d-32)>>3)*16 + 8 + (d&7)
//   so each 16-col C-fragment holds RoPE pairs at lanes cc / cc^8.
// blocks [0,4096) -> x ; [4096,10240) -> weights (1024 blocks each).
// ---------------------------------------------------------------------------
__global__ __launch_bounds__(256)
void pack_all_kernel(const float* __restrict__ x,
                     const float* __restrict__ w0, const float* __restrict__ w1,
                     const float* __restrict__ w2, const float* __restrict__ w3,
                     const float* __restrict__ w4, const float* __restrict__ w5,
                     unsigned short* __restrict__ dstX, unsigned short* __restrict__ dstW)
{
    const float* src;
    unsigned short* dst;
    int gid;
    bool ilv = false;
    if (blockIdx.x < 4096) {
        src = x; dst = dstX;
        gid = blockIdx.x * 256 + threadIdx.x;
    } else {
        int wi = (blockIdx.x - 4096) >> 10;
        const float* srcs[6] = {w0, w1, w2, w3, w4, w5};
        src = srcs[wi];
        dst = dstW + (size_t)wi * 1024 * 2048;
        gid = ((blockIdx.x - 4096) & 1023) * 256 + threadIdx.x;
        ilv = (wi >= 1 && wi <= 4);   // Wq, Wk, Wq2, Wk2
    }
    int e   = gid * 4;
    int row = e >> 10;
    int col = e & 1023;
    float4 f = *(const float4*)(src + (size_t)row * 1024 + col);
    ushort4 hi;
    hi.x = f2bf(f.x);
    hi.y = f2bf(f.y);
    hi.z = f2bf(f.z);
    hi.w = f2bf(f.w);
    int drow = row;
    if (ilv) {
        int hh = row >> 6, d = row & 63;
        int dd = (d < 32) ? ((d >> 3) * 16 + (d & 7))
                          : (((d - 32) >> 3) * 16 + 8 + (d & 7));
        drow = hh * 64 + dd;
    }
    *(ushort4*)(dst + (size_t)drow * 2048 + col) = hi;
}

// ---------------------------------------------------------------------------
// qkv GEMM — 1-TERM hi-only, K=1024 (UNCHANGED):
//   C[4096][5120] = Xhi[4096][1024] . Whi[5120][1024]^T
// Tile 256x320, K-tile 64, 8 waves 2M x 4N, counted vmcnt(8), 16 K-tiles.
// ---------------------------------------------------------------------------
#define VMW(N) asm volatile("s_waitcnt vmcnt(" #N ")" ::: "memory")
#define LGKM0  asm volatile("s_waitcnt lgkmcnt(0)" ::: "memory")

__global__ __launch_bounds__(512, 2)
void gemm_qkv(const unsigned short* __restrict__ Ap,
              const unsigned short* __restrict__ Bp,
              unsigned short* __restrict__ Ch, unsigned short* __restrict__ Vt)
{
    __shared__ __align__(16) unsigned short A0s[2][8192];    // [256][32] each
    __shared__ __align__(16) unsigned short A1s[2][8192];
    __shared__ __align__(16) unsigned short B0s[2][10240];   // [320][32] each
    __shared__ __align__(16) unsigned short B1s[2][10240];

    const int t    = threadIdx.x;
    const int lane = t & 63;
    const int w    = t >> 6;
    const int wm   = w >> 2;          // M-half (0..1): 128 rows
    const int wn   = w & 3;           // N-quarter (0..3): 80 cols
    const int s    = lane & 15;
    const int g    = (lane >> 4) & 3;
    const int row0 = blockIdx.x * 256;
    const int col0 = blockIdx.y * 320;

    // read-side swizzled offsets (element units, 32-wide rows)
    const int cofs  = ((g ^ ((lane >> 1) & 3)) << 3);
    const int addrA = (wm * 128 + s) * 32 + cofs;   // + ii*512
    const int addrB = (wn * 80 + s) * 32 + cofs;    // + nf*512

    // stage-side pre-swizzled global source base (logical chunk per thread)
    const int alc = (t & 3) ^ ((t >> 3) & 3);
    const unsigned short* Ag = Ap + (size_t)(row0 + (t >> 2)) * 2048 + alc * 8;
    const unsigned short* Bg = Bp + (size_t)(col0 + (t >> 2)) * 2048 + alc * 8;

#define STAGE_A(dst, kofs) {                                                                              \
    __builtin_amdgcn_global_load_lds((gvoid*)(Ag + (kofs)),              (lvoid*)((dst) + t * 8),        16, 0, 0); \
    __builtin_amdgcn_global_load_lds((gvoid*)(Ag + (kofs) + 128 * 2048), (lvoid*)((dst) + 4096 + t * 8), 16, 0, 0); }

#define STAGE_B(dst, kofs) {                                                                              \
    __builtin_amdgcn_global_load_lds((gvoid*)(Bg + (kofs)),              (lvoid*)((dst) + t * 8),        16, 0, 0); \
    __builtin_amdgcn_global_load_lds((gvoid*)(Bg + (kofs) + 128 * 2048), (lvoid*)((dst) + 4096 + t * 8), 16, 0, 0); \
    if (t < 256)                                                                                          \
    __builtin_amdgcn_global_load_lds((gvoid*)(Bg + (kofs) + 256 * 2048), (lvoid*)((dst) + 8192 + t * 8), 16, 0, 0); }

    floatx4 acc[8][5];
    #pragma unroll
    for (int ii = 0; ii < 8; ++ii)
        #pragma unroll
        for (int nf = 0; nf < 5; ++nf)
            acc[ii][nf] = (floatx4)(0.0f);

    // ---- prologue: tile0 (kh0,kh1) and tile1 (kh0) ----
    STAGE_A(A0s[0], 0);
    STAGE_B(B0s[0], 0);
    STAGE_A(A1s[0], 32);
    STAGE_B(B1s[0], 32);
    STAGE_A(A0s[1], 64);
    STAGE_B(B0s[1], 64);
    VMW(4);                       // tile0 fully landed (newest 4-5 = tile1 kh0)
    __builtin_amdgcn_s_barrier();
    __builtin_amdgcn_sched_barrier(0);

#define MFMA_CLUSTER(IOFS)                                                                      \
    __builtin_amdgcn_s_setprio(1);                                                              \
    _Pragma("unroll")                                                                           \
    for (int ii = 0; ii < 4; ++ii)                                                              \
        _Pragma("unroll")                                                                       \
        for (int nf = 0; nf < 5; ++nf)                                                          \
            acc[(IOFS) + ii][nf] = __builtin_amdgcn_mfma_f32_16x16x32_bf16(af[ii], bf[nf], acc[(IOFS) + ii][nf], 0, 0, 0); \
    __builtin_amdgcn_s_setprio(0);

#define TILE_BODY(TAU, DO12, DO34, W2, W4)                                                      \
{                                                                                               \
    const int cur_ = (TAU) & 1;                                                                 \
    const unsigned short* a0k = A0s[cur_];                                                      \
    const unsigned short* a1k = A1s[cur_];                                                      \
    const unsigned short* b0k = B0s[cur_];                                                      \
    const unsigned short* b1k = B1s[cur_];                                                      \
    short8 af[4], bf[5];                                                                        \
    /* ---- p1: kh0, M-half0 + B-kh0 read ; stage (TAU+1) A-kh1 ---- */                         \
    _Pragma("unroll")                                                                           \
    for (int ii = 0; ii < 4; ++ii) af[ii] = *(const short8*)&a0k[addrA + ii * 512];             \
    _Pragma("unroll")                                                                           \
    for (int nf = 0; nf < 5; ++nf) bf[nf] = *(const short8*)&b0k[addrB + nf * 512];             \
    if (DO12) STAGE_A(A1s[cur_ ^ 1], ((TAU) + 1) * 64 + 32);                                    \
    LGKM0;                                                                                      \
    __builtin_amdgcn_s_barrier();                                                               \
    __builtin_amdgcn_sched_barrier(0);                                                          \
    MFMA_CLUSTER(0)                                                                             \
    /* ---- p2: kh0, M-half1 ; stage (TAU+1) B-kh1 ; vmcnt ---- */                              \
    _Pragma("unroll")                                                                           \
    for (int ii = 0; ii < 4; ++ii) af[ii] = *(const short8*)&a0k[addrA + (ii + 4) * 512];       \
    if (DO12) STAGE_B(B1s[cur_ ^ 1], ((TAU) + 1) * 64 + 32);                                    \
    LGKM0;                                                                                      \
    W2;                                                                                         \
    __builtin_amdgcn_s_barrier();                                                               \
    __builtin_amdgcn_sched_barrier(0);                                                          \
    MFMA_CLUSTER(4)                                                                             \
    /* ---- p3: kh1, M-half0 + B-kh1 read ; stage (TAU+2) A-kh0 ---- */                         \
    _Pragma("unroll")                                                                           \
    for (int ii = 0; ii < 4; ++ii) af[ii] = *(const short8*)&a1k[addrA + ii * 512];             \
    _Pragma("unroll")                                                                           \
    for (int nf = 0; nf < 5; ++nf) bf[nf] = *(const short8*)&b1k[addrB + nf * 512];             \
    if (DO34) STAGE_A(A0s[cur_], ((TAU) + 2) * 64);                                             \
    LGKM0;                                                                                      \
    __builtin_amdgcn_s_barrier();                                                               \
    __builtin_amdgcn_sched_barrier(0);                                                          \
    MFMA_CLUSTER(0)                                                                             \
    /* ---- p4: kh1, M-half1 ; stage (TAU+2) B-kh0 ; vmcnt ---- */                              \
    _Pragma("unroll")                                                                           \
    for (int ii = 0; ii < 4; ++ii) af[ii] = *(const short8*)&a1k[addrA + (ii + 4) * 512];       \
    if (DO34) STAGE_B(B0s[cur_], ((TAU) + 2) * 64);                                             \
    LGKM0;                                                                                      \
    W4;                                                                                        \
    __builtin_amdgcn_s_barrier();                                                               \
    __builtin_amdgcn_sched_barrier(0);                                                          \
    MFMA_CLUSTER(4)                                                                             \
}

    #pragma unroll 2
    for (int tau = 0; tau < 14; ++tau)
        TILE_BODY(tau, 1, 1, VMW(8), VMW(8));
    TILE_BODY(14, 1, 0, VMW(8), VMW(4));
    TILE_BODY(15, 0, 0, VMW(0), ((void)0));

#undef TILE_BODY
#undef MFMA_CLUSTER
#undef STAGE_A
#undef STAGE_B

    // ---- epilogue: lane-local RoPE (+1/64 q-scale); V transposed ----
    const int cr = (lane >> 4) * 4;
    const int cc = lane & 15;
    const int rwbase = row0 + wm * 128;
    const float L2C = -0.41524101186092029f;  // -log2(10000)/32

    #pragma unroll
    for (int nf = 0; nf < 5; ++nf) {
        const int cg = col0 + wn * 80 + nf * 16;  // global col of this frag
        const int p  = cg >> 10;                  // 0=q 1=k 2=q2 3=k2 4=v
        const int h  = (cg >> 6) & 15;
        const int f  = (cg >> 4) & 3;
        if (p < 4) {
            const float sc  = (p == 0 || p == 2) ? 0.015625f : 1.0f;
            const float inv = exp2f((float)(f * 8 + (cc & 7)) * L2C);
            unsigned short* hp = Ch + (size_t)p * 4194304;
            #pragma unroll
            for (int ii = 0; ii < 8; ++ii) {
                int r0  = rwbase + ii * 16 + cr;
                int bhi = ((r0 >> 11) << 4) + h;
                size_t base = ((size_t)bhi * 2048 + (r0 & 2047)) * 64;
                #pragma unroll
                for (int rr = 0; rr < 4; ++rr) {
                    float tt = (float)((r0 + rr) & 2047);
                    float s0, c0;
                    __sincosf(tt * inv, &s0, &c0);
                    float x  = acc[ii][nf][rr];
                    float xp = __shfl_xor(x, 8, 64);
                    float y  = (cc < 8) ? (x * c0 + xp * s0) : (x * c0 - xp * s0);
                    hp[base + (size_t)rr * 64 + (f * 16 + cc)] = f2bf(y * sc);
                }
            }
        } else {
            #pragma unroll
            for (int ii = 0; ii < 8; ++ii) {
                int r0  = rwbase + ii * 16 + cr;
                int bhi = ((r0 >> 11) << 4) + h;
                int d   = f * 16 + cc;
                ushort4 o;
                o.x = f2bf(acc[ii][nf][0]); o.y = f2bf(acc[ii][nf][1]);
                o.z = f2bf(acc[ii][nf][2]); o.w = f2bf(acc[ii][nf][3]);
                *(ushort4*)(Vt + ((size_t)bhi * 64 + d) * 2048 + (r0 & 2047)) = o;
            }
        }
    }
}

// ---------------------------------------------------------------------------
// Output projection — 1-TERM bf16: C = Ah . Bh^T, fp32 out (UNCHANGED).
// 128x128 tile, grid (32,8) = 256 blocks = 1/CU, 4 waves (wave-tile 64x64),
// 16 MFMA : 8 ds_reads per K-step, 16 KB LDS, chunk-XOR swizzle, 2 barriers.
// ---------------------------------------------------------------------------
__global__ __launch_bounds__(256)
void gemm_proj(const unsigned short* __restrict__ Ap,
               const unsigned short* __restrict__ Bp,
               float* __restrict__ Cf)
{
    __shared__ __align__(16) unsigned short Ah[128 * 32];
    __shared__ __align__(16) unsigned short Bh[128 * 32];

    const int t    = threadIdx.x;
    const int lane = t & 63;
    const int s    = lane & 15;
    const int row0 = blockIdx.x * 128;
    const int col0 = blockIdx.y * 128;
    const int m0   = ((t >> 6) >> 1) * 64;
    const int n0   = ((t >> 6) & 1) * 64;

    floatx4 acc[4][4];
    #pragma unroll
    for (int i = 0; i < 4; ++i)
        #pragma unroll
        for (int j = 0; j < 4; ++j)
            acc[i][j] = (floatx4)(0.0f);

    const int sr  = t >> 2;
    const int skx = ((t & 3) ^ ((t >> 3) & 3)) * 8;
    char* dA  = (char*)Ah + (size_t)t * 16;
    char* dB  = (char*)Bh + (size_t)t * 16;
    const size_t arow = (size_t)(row0 + sr) * 2048 + skx;
    const size_t brow = (size_t)(col0 + sr) * 2048 + skx;

    #define ISSUE(k0)                                                                         \
    {                                                                                         \
        const unsigned short* ga = Ap + arow + (k0);                                          \
        const unsigned short* gb = Bp + brow + (k0);                                          \
        __builtin_amdgcn_global_load_lds((gvoid*)ga,                 (lvoid*)dA,          16, 0, 0); \
        __builtin_amdgcn_global_load_lds((gvoid*)(ga + 64*2048),     (lvoid*)(dA + 4096), 16, 0, 0); \
        __builtin_amdgcn_global_load_lds((gvoid*)gb,                 (lvoid*)dB,          16, 0, 0); \
        __builtin_amdgcn_global_load_lds((gvoid*)(gb + 64*2048),     (lvoid*)(dB + 4096), 16, 0, 0); \
    }

    const int cofs = (((lane >> 4) ^ ((lane >> 1) & 3)) << 3);

    ISSUE(0);
    for (int ks = 0; ks < 32; ++ks) {
        __syncthreads();
        short8 ahf[4], bhf[4];
        #pragma unroll
        for (int i = 0; i < 4; ++i)
            ahf[i] = *(const short8*)&Ah[(m0 + i * 16 + s) * 32 + cofs];
        #pragma unroll
        for (int j = 0; j < 4; ++j)
            bhf[j] = *(const short8*)&Bh[(n0 + j * 16 + s) * 32 + cofs];
        #pragma unroll
        for (int i = 0; i < 4; ++i)
            #pragma unroll
            for (int j = 0; j < 4; ++j)
                acc[i][j] = __builtin_amdgcn_mfma_f32_16x16x32_bf16(ahf[i], bhf[j], acc[i][j], 0, 0, 0);
        __syncthreads();
        if (ks + 1 < 32) ISSUE((ks + 1) * 32);
    }
    #undef ISSUE

    const int cr = (lane >> 4) * 4;
    const int cc = lane & 15;
    #pragma unroll
    for (int i = 0; i < 4; ++i)
        #pragma unroll
        for (int j = 0; j < 4; ++j) {
            int r = row0 + m0 + i * 16 + cr;
            int c = col0 + n0 + j * 16 + cc;
            #pragma unroll
            for (int rr = 0; rr < 4; ++rr)
                Cf[(size_t)(r + rr) * 1024 + c] = acc[i][j][rr];
        }
}

// ---------------------------------------------------------------------------
// MFMA bilinear causal attention — ONE Q-TILE PER BLOCK, 2 blocks/CU TLP.
// No softmax => q-tiles are fully independent (disjoint zout rows), so the
// heavy/light pair that round-9 ran SEQUENTIALLY in one block now runs as
// two CO-RESIDENT blocks: grid 512, bid<256 -> heavy (qt=15-pr), bid>=256 ->
// light (qt=pr). Round-robin dispatch puts bid and bid+256 on the same CU
// ((bid+256)&7 same XCD, (bid/8+32)%32 same CU slot) -> per-CU work stays
// exactly 17 tile-iters AND one block's barriers/LDS latency hide under the
// other block's MFMA (4 waves/SIMD, was 2). LDS single-buffer 80 KB so two
// blocks fit exactly (160 KB). T14 prefetch kept; 3 barriers/iter;
// z written as single bf16. Mapping is perf-only — any dispatch order is
// still correct (blocks independent).
// ---------------------------------------------------------------------------
__global__ __launch_bounds__(512, 2)
void attn_mfma(const unsigned short* __restrict__ qh, const unsigned short* __restrict__ q2h,
               const unsigned short* __restrict__ kh, const unsigned short* __restrict__ k2h,
               const unsigned short* __restrict__ vt, unsigned short* __restrict__ zout)
{
    __shared__ __align__(16) unsigned short smem[40960];   // 80 KB
    unsigned short* qs  = smem;              // [128][64] rot8 (init only)
    unsigned short* q2s = smem + 8192;
    unsigned short* psq = smem;              // [128][128] rot16, overlays qs/q2s
    unsigned short* ks  = smem + 16384;      // [128][64] rot8
    unsigned short* k2s = smem + 24576;
    unsigned short* vts = smem + 32768;      // [64][128] rot16

    const int bid  = blockIdx.x;
    const int half = bid >> 8;          // 0 = heavy, 1 = light
    const int r    = bid & 255;
    const int xcd  = r & 7;
    const int slot = r >> 3;            // 0..31
    const int hh   = slot >> 3;         // 0..3
    const int pr   = slot & 7;          // 0..7 (pair index)
    const int bh   = xcd * 4 + hh;
    const int qt   = half ? pr : (15 - pr);
    const int t  = threadIdx.x;
    const int lane = t & 63;
    const int w    = t >> 6;          // 0..7
    const int s    = lane & 15;
    const int g    = lane >> 4;
    const int mk   = (w >> 1) * 32;   // 4-way k-split: 32 rows/wave
    const int nq   = (w & 1) * 64;    // 2-way q-split

    const int b = bh >> 4, h = bh & 15;

    short8 kf[2], k2f[2], vf[2];

#define LOADKV(TK) {                                                                \
    const unsigned short* kb  = kh  + ((size_t)bh * 2048 + (TK) * 128) * 64;        \
    const unsigned short* k2b = k2h + ((size_t)bh * 2048 + (TK) * 128) * 64;        \
    const unsigned short* vb  = vt  + (size_t)bh * 131072 + (TK) * 128;             \
    const int krow_ = t >> 2;                                                       \
    const int vd_   = t >> 3;                                                       \
    _Pragma("unroll")                                                               \
    for (int c = 0; c < 2; ++c) {                                                   \
        int cg_ = (t & 3) * 2 + c;                                                  \
        kf[c]  = *(const short8*)(kb  + (size_t)krow_ * 64 + cg_ * 8);              \
        k2f[c] = *(const short8*)(k2b + (size_t)krow_ * 64 + cg_ * 8);              \
        int cg16_ = (t & 7) * 2 + c;                                                \
        vf[c]  = *(const short8*)(vb + (size_t)vd_ * 2048 + cg16_ * 8);             \
    } }

    // issue first K/V tile loads early: latency overlaps q staging + hoist
    LOADKV(0);

    // ---- stage q, q2 for this q-tile, then hoist frags to registers ----
    {
        const unsigned short* qb  = qh  + ((size_t)bh * 2048 + qt * 128) * 64;
        const unsigned short* q2b = q2h + ((size_t)bh * 2048 + qt * 128) * 64;
        const int row = t >> 2;                    // 0..127
        #pragma unroll
        for (int c = 0; c < 2; ++c) {
            int cg  = (t & 3) * 2 + c;             // 0..7
            short8 a  = *(const short8*)(qb  + (size_t)row * 64 + cg * 8);
            short8 a2 = *(const short8*)(q2b + (size_t)row * 64 + cg * 8);
            int cgm = (cg + row) & 7;
            *(short8*)&qs [row * 64 + cgm * 8] = a;
            *(short8*)&q2s[row * 64 + cgm * 8] = a2;
        }
    }
    __syncthreads();
    short8 bq[2][4], bq2[2][4];
    #pragma unroll
    for (int kstep = 0; kstep < 2; ++kstep) {
        const int gl = kstep * 4 + g;
        #pragma unroll
        for (int j = 0; j < 4; ++j) {
            int row = nq + j * 16 + s;
            int a = row * 64 + ((gl + row) & 7) * 8;
            bq[kstep][j]  = *(const short8*)&qs [a];
            bq2[kstep][j] = *(const short8*)&q2s[a];
        }
    }

    floatx4 zac[4];
    #pragma unroll
    for (int j = 0; j < 4; ++j)
        zac[j] = (floatx4)(0.0f);

    for (int tk = 0; tk <= qt; ++tk) {
        __syncthreads();   // b0: prev PV done (psq/vts); prev S done (ks/k2s); q-hoist done
        {
            // ds_writes(tk): consumes kf/k2f/vf loaded one iteration ago
            const int krow = t >> 2;
            const int vd   = t >> 3;
            #pragma unroll
            for (int c = 0; c < 2; ++c) {
                int cg  = (t & 3) * 2 + c;
                int cgm = (cg + krow) & 7;
                *(short8*)&ks [krow * 64 + cgm * 8] = kf[c];
                *(short8*)&k2s[krow * 64 + cgm * 8] = k2f[c];
                int cg16  = (t & 7) * 2 + c;
                int cgm16 = (cg16 + vd) & 15;
                *(short8*)&vts[vd * 128 + cgm16 * 8] = vf[c];
            }
        }
        __syncthreads();   // b1: tiles visible

        // ---- T14: issue next tile's K/V loads; latency hides under S+P+PV
        if (tk < qt) LOADKV(tk + 1);
        __builtin_amdgcn_sched_barrier(0);

        // ---- S + P, i-outer (2 frags of 16 k-rows per wave) ----
        #pragma unroll
        for (int i = 0; i < 2; ++i) {
            floatx4 a1[4], a2[4];
            #pragma unroll
            for (int j = 0; j < 4; ++j) { a1[j] = (floatx4)(0.0f); a2[j] = (floatx4)(0.0f); }
            #pragma unroll
            for (int kstep = 0; kstep < 2; ++kstep) {
                const int gl = kstep * 4 + g;
                int row = mk + i * 16 + s;
                int a = row * 64 + ((gl + row) & 7) * 8;
                short8 ak  = *(const short8*)&ks [a];
                short8 ak2 = *(const short8*)&k2s[a];
                #pragma unroll
                for (int j = 0; j < 4; ++j) {
                    a1[j] = __builtin_amdgcn_mfma_f32_16x16x32_bf16(ak,  bq[kstep][j],  a1[j], 0, 0, 0);
                    a2[j] = __builtin_amdgcn_mfma_f32_16x16x32_bf16(ak2, bq2[kstep][j], a2[j], 0, 0, 0);
                }
            }
            // P-write for this i: psq region unread by anyone during the loop
            const int kl0   = mk + i * 16 + g * 4;
            const int chunk = kl0 >> 3;
            const int sub   = kl0 & 7;
            if (tk < qt) {
                #pragma unroll
                for (int j = 0; j < 4; ++j) {
                    const int ql = nq + j * 16 + s;
                    ushort4 pw;
                    pw.x = f2bf(a1[j][0] * a2[j][0]);
                    pw.y = f2bf(a1[j][1] * a2[j][1]);
                    pw.z = f2bf(a1[j][2] * a2[j][2]);
                    pw.w = f2bf(a1[j][3] * a2[j][3]);
                    *(ushort4*)&psq[ql * 128 + ((chunk + ql) & 15) * 8 + sub] = pw;
                }
            } else {
                #pragma unroll
                for (int j = 0; j < 4; ++j) {
                    const int ql = nq + j * 16 + s;
                    ushort4 pw;
                    pw.x = (kl0 + 0 <= ql) ? f2bf(a1[j][0] * a2[j][0]) : (unsigned short)0;
                    pw.y = (kl0 + 1 <= ql) ? f2bf(a1[j][1] * a2[j][1]) : (unsigned short)0;
                    pw.z = (kl0 + 2 <= ql) ? f2bf(a1[j][2] * a2[j][2]) : (unsigned short)0;
                    pw.w = (kl0 + 3 <= ql) ? f2bf(a1[j][3] * a2[j][3]) : (unsigned short)0;
                    *(ushort4*)&psq[ql * 128 + ((chunk + ql) & 15) * 8 + sub] = pw;
                }
            }
        }

        __syncthreads();   // b2: psq visible

        // ---- PV: z[q][d] += P[q][k] * vT[d][k] ; wave owns 16 q-rows ----
        const int wm0 = w * 16;
        #pragma unroll
        for (int kstep = 0; kstep < 4; ++kstep) {
            const int cbase = kstep * 4 + g;
            short8 ap, bv[4];
            {
                int q = wm0 + s;
                ap = *(const short8*)&psq[q * 128 + ((cbase + q) & 15) * 8];
            }
            #pragma unroll
            for (int jd = 0; jd < 4; ++jd) {
                int d = jd * 16 + s;
                bv[jd] = *(const short8*)&vts[d * 128 + ((cbase + d) & 15) * 8];
            }
            #pragma unroll
            for (int jd = 0; jd < 4; ++jd)
                zac[jd] = __builtin_amdgcn_mfma_f32_16x16x32_bf16(ap, bv[jd], zac[jd], 0, 0, 0);
        }
    }

    // ---- epilogue: z -> single bf16 into zout[4096][2048] (hi cols) ----
    const size_t zrow0 = (size_t)(b * TSEQ + qt * 128);
    #pragma unroll
    for (int j = 0; j < 4; ++j)
        #pragma unroll
        for (int r2 = 0; r2 < 4; ++r2) {
            size_t row = zrow0 + w * 16 + g * 4 + r2;
            int col = h * 64 + j * 16 + s;
            zout[row * 2048 + col] = f2bf(zac[j][r2]);
        }
#undef LOADKV
}

// ---------------------------------------------------------------------------
extern "C" void kernel_launch(void* const* d_in, const int* in_sizes, int n_in,
                              void* d_out, int out_size, void* d_ws, size_t ws_size,
                              hipStream_t stream)
{
    const float* x     = (const float*)d_in[0];
    const float* Wq    = (const float*)d_in[1];
    const float* Wk    = (const float*)d_in[2];
    const float* Wq2   = (const float*)d_in[3];
    const float* Wk2   = (const float*)d_in[4];
    const float* Wv    = (const float*)d_in[5];
    const float* Wproj = (const float*)d_in[6];

    // workspace (bytes):
    //   Xp    bf16 [4096][2048] (x-hi, later z single-bf16) @ 0       (16,777,216)
    //   Wp    bf16 [6144][2048]                          @ 16,777,216 (25,165,824)
    //         rows [0,1024)    = Wproj [hi|dead]
    //         rows [1024,6144) = Wq,Wk,Wq2,Wk2 (head-interleaved), Wv [hi|dead]
    //   heads bf16 4x[32][2048][64] (q,k,q2,k2)          @ 41,943,040 (33,554,432)
    //   vt    bf16 [32][64][2048]                        @ 75,497,472 ( 8,388,608)
    unsigned short* Xp    = (unsigned short*)d_ws;
    unsigned short* Wp    = (unsigned short*)((char*)d_ws + 16777216);
    unsigned short* heads = (unsigned short*)((char*)d_ws + 41943040);
    unsigned short* vt    = (unsigned short*)((char*)d_ws + 75497472);

    const size_t HS = (size_t)32 * 2048 * 64;
    unsigned short* qh  = heads;
    unsigned short* kh  = heads + 1 * HS;
    unsigned short* q2h = heads + 2 * HS;
    unsigned short* k2h = heads + 3 * HS;

    pack_all_kernel<<<10240, 256, 0, stream>>>(x, Wproj, Wq, Wk, Wq2, Wk2, Wv, Xp, Wp);
    gemm_qkv<<<dim3(16, 16), 512, 0, stream>>>(Xp, Wp + (size_t)1024 * 2048, heads, vt);
    attn_mfma<<<512, 512, 0, stream>>>(qh, q2h, kh, k2h, vt, Xp);
    gemm_proj<<<dim3(32, 8), 256, 0, stream>>>(Xp, Wp, (float*)d_out);
}

// Round 14
// 202.673 us; speedup vs baseline: 1.0849x; 1.0849x over previous
//
#include <hip/hip_runtime.h>
#include <hip/hip_bf16.h>

#define TSEQ 2048
#define NHEAD 16
#define DM 1024
#define NBATCH 2
#define MTOK (NBATCH * TSEQ)   // 4096

typedef __attribute__((ext_vector_type(8))) short short8;
typedef __attribute__((ext_vector_type(4))) float floatx4;
typedef __attribute__((address_space(1))) const void gvoid;
typedef __attribute__((address_space(3))) void lvoid;

static __device__ __forceinline__ unsigned short f2bf(float f) {
    unsigned int u = __float_as_uint(f);
    return (unsigned short)((u + 0x7fffu + ((u >> 16) & 1u)) >> 16);
}
static __device__ __forceinline__ float bf2f(unsigned short h) {
    return __uint_as_float(((unsigned int)h) << 16);
}

// ---------------------------------------------------------------------------
// Pack x and the 6 weight matrices to bf16 rows (single precision level).
//   x, Wproj, Wq..Wv -> [hi(1024) | dead]
//   Wq,Wk,Wq2,Wk2 rows additionally PER-HEAD INTERLEAVED:
//     d<32 -> (d>>3)*16 + (d&7) ; d>=32 -> ((d-32)>>3)*16 + 8 + (d&7)
//   so each 16-col C-fragment holds RoPE pairs at lanes cc / cc^8.
// blocks [0,4096) -> x ; [4096,10240) -> weights (1024 blocks each).
// ---------------------------------------------------------------------------
__global__ __launch_bounds__(256)
void pack_all_kernel(const float* __restrict__ x,
                     const float* __restrict__ w0, const float* __restrict__ w1,
                     const float* __restrict__ w2, const float* __restrict__ w3,
                     const float* __restrict__ w4, const float* __restrict__ w5,
                     unsigned short* __restrict__ dstX, unsigned short* __restrict__ dstW)
{
    const float* src;
    unsigned short* dst;
    int gid;
    bool ilv = false;
    if (blockIdx.x < 4096) {
        src = x; dst = dstX;
        gid = blockIdx.x * 256 + threadIdx.x;
    } else {
        int wi = (blockIdx.x - 4096) >> 10;
        const float* srcs[6] = {w0, w1, w2, w3, w4, w5};
        src = srcs[wi];
        dst = dstW + (size_t)wi * 1024 * 2048;
        gid = ((blockIdx.x - 4096) & 1023) * 256 + threadIdx.x;
        ilv = (wi >= 1 && wi <= 4);   // Wq, Wk, Wq2, Wk2
    }
    int e   = gid * 4;
    int row = e >> 10;
    int col = e & 1023;
    float4 f = *(const float4*)(src + (size_t)row * 1024 + col);
    ushort4 hi;
    hi.x = f2bf(f.x);
    hi.y = f2bf(f.y);
    hi.z = f2bf(f.z);
    hi.w = f2bf(f.w);
    int drow = row;
    if (ilv) {
        int hh = row >> 6, d = row & 63;
        int dd = (d < 32) ? ((d >> 3) * 16 + (d & 7))
                          : (((d - 32) >> 3) * 16 + 8 + (d & 7));
        drow = hh * 64 + dd;
    }
    *(ushort4*)(dst + (size_t)drow * 2048 + col) = hi;
}

// ---------------------------------------------------------------------------
// qkv GEMM — 1-TERM hi-only, K=1024, + T1 XCD-AWARE GRID SWIZZLE:
//   C[4096][5120] = Xhi[4096][1024] . Whi[5120][1024]^T
// Grid is 1-D 256; decode xcd=bid&7, q=bid>>3, col-panel y=xcd*2+(q&1),
// row-panel x=q>>1 (bijective). Each XCD owns 2 B-panels (1.31 MB < 4 MB L2,
// was all 16 -> 10.5 MB) so B is fetched ~once per XCD; A streams via L3.
// Tile 256x320, K-tile 64, 8 waves 2M x 4N, counted vmcnt(8), 16 K-tiles.
// ---------------------------------------------------------------------------
#define VMW(N) asm volatile("s_waitcnt vmcnt(" #N ")" ::: "memory")
#define LGKM0  asm volatile("s_waitcnt lgkmcnt(0)" ::: "memory")

__global__ __launch_bounds__(512, 2)
void gemm_qkv(const unsigned short* __restrict__ Ap,
              const unsigned short* __restrict__ Bp,
              unsigned short* __restrict__ Ch, unsigned short* __restrict__ Vt)
{
    __shared__ __align__(16) unsigned short A0s[2][8192];    // [256][32] each
    __shared__ __align__(16) unsigned short A1s[2][8192];
    __shared__ __align__(16) unsigned short B0s[2][10240];   // [320][32] each
    __shared__ __align__(16) unsigned short B1s[2][10240];

    const int t    = threadIdx.x;
    const int lane = t & 63;
    const int w    = t >> 6;
    const int wm   = w >> 2;          // M-half (0..1): 128 rows
    const int wn   = w & 3;           // N-quarter (0..3): 80 cols
    const int s    = lane & 15;
    const int g    = (lane >> 4) & 3;
    const int bid  = blockIdx.x;
    const int xcd  = bid & 7;
    const int q    = bid >> 3;        // 0..31
    const int row0 = (q >> 1) * 256;            // row-panel 0..15
    const int col0 = (xcd * 2 + (q & 1)) * 320; // col-panel 0..15 (2 per XCD)

    // read-side swizzled offsets (element units, 32-wide rows)
    const int cofs  = ((g ^ ((lane >> 1) & 3)) << 3);
    const int addrA = (wm * 128 + s) * 32 + cofs;   // + ii*512
    const int addrB = (wn * 80 + s) * 32 + cofs;    // + nf*512

    // stage-side pre-swizzled global source base (logical chunk per thread)
    const int alc = (t & 3) ^ ((t >> 3) & 3);
    const unsigned short* Ag = Ap + (size_t)(row0 + (t >> 2)) * 2048 + alc * 8;
    const unsigned short* Bg = Bp + (size_t)(col0 + (t >> 2)) * 2048 + alc * 8;

#define STAGE_A(dst, kofs) {                                                                              \
    __builtin_amdgcn_global_load_lds((gvoid*)(Ag + (kofs)),              (lvoid*)((dst) + t * 8),        16, 0, 0); \
    __builtin_amdgcn_global_load_lds((gvoid*)(Ag + (kofs) + 128 * 2048), (lvoid*)((dst) + 4096 + t * 8), 16, 0, 0); }

#define STAGE_B(dst, kofs) {                                                                              \
    __builtin_amdgcn_global_load_lds((gvoid*)(Bg + (kofs)),              (lvoid*)((dst) + t * 8),        16, 0, 0); \
    __builtin_amdgcn_global_load_lds((gvoid*)(Bg + (kofs) + 128 * 2048), (lvoid*)((dst) + 4096 + t * 8), 16, 0, 0); \
    if (t < 256)                                                                                          \
    __builtin_amdgcn_global_load_lds((gvoid*)(Bg + (kofs) + 256 * 2048), (lvoid*)((dst) + 8192 + t * 8), 16, 0, 0); }

    floatx4 acc[8][5];
    #pragma unroll
    for (int ii = 0; ii < 8; ++ii)
        #pragma unroll
        for (int nf = 0; nf < 5; ++nf)
            acc[ii][nf] = (floatx4)(0.0f);

    // ---- prologue: tile0 (kh0,kh1) and tile1 (kh0) ----
    STAGE_A(A0s[0], 0);
    STAGE_B(B0s[0], 0);
    STAGE_A(A1s[0], 32);
    STAGE_B(B1s[0], 32);
    STAGE_A(A0s[1], 64);
    STAGE_B(B0s[1], 64);
    VMW(4);                       // tile0 fully landed (newest 4-5 = tile1 kh0)
    __builtin_amdgcn_s_barrier();
    __builtin_amdgcn_sched_barrier(0);

#define MFMA_CLUSTER(IOFS)                                                                      \
    __builtin_amdgcn_s_setprio(1);                                                              \
    _Pragma("unroll")                                                                           \
    for (int ii = 0; ii < 4; ++ii)                                                              \
        _Pragma("unroll")                                                                       \
        for (int nf = 0; nf < 5; ++nf)                                                          \
            acc[(IOFS) + ii][nf] = __builtin_amdgcn_mfma_f32_16x16x32_bf16(af[ii], bf[nf], acc[(IOFS) + ii][nf], 0, 0, 0); \
    __builtin_amdgcn_s_setprio(0);

#define TILE_BODY(TAU, DO12, DO34, W2, W4)                                                      \
{                                                                                               \
    const int cur_ = (TAU) & 1;                                                                 \
    const unsigned short* a0k = A0s[cur_];                                                      \
    const unsigned short* a1k = A1s[cur_];                                                      \
    const unsigned short* b0k = B0s[cur_];                                                      \
    const unsigned short* b1k = B1s[cur_];                                                      \
    short8 af[4], bf[5];                                                                        \
    /* ---- p1: kh0, M-half0 + B-kh0 read ; stage (TAU+1) A-kh1 ---- */                         \
    _Pragma("unroll")                                                                           \
    for (int ii = 0; ii < 4; ++ii) af[ii] = *(const short8*)&a0k[addrA + ii * 512];             \
    _Pragma("unroll")                                                                           \
    for (int nf = 0; nf < 5; ++nf) bf[nf] = *(const short8*)&b0k[addrB + nf * 512];             \
    if (DO12) STAGE_A(A1s[cur_ ^ 1], ((TAU) + 1) * 64 + 32);                                    \
    LGKM0;                                                                                      \
    __builtin_amdgcn_s_barrier();                                                               \
    __builtin_amdgcn_sched_barrier(0);                                                          \
    MFMA_CLUSTER(0)                                                                             \
    /* ---- p2: kh0, M-half1 ; stage (TAU+1) B-kh1 ; vmcnt ---- */                              \
    _Pragma("unroll")                                                                           \
    for (int ii = 0; ii < 4; ++ii) af[ii] = *(const short8*)&a0k[addrA + (ii + 4) * 512];       \
    if (DO12) STAGE_B(B1s[cur_ ^ 1], ((TAU) + 1) * 64 + 32);                                    \
    LGKM0;                                                                                      \
    W2;                                                                                         \
    __builtin_amdgcn_s_barrier();                                                               \
    __builtin_amdgcn_sched_barrier(0);                                                          \
    MFMA_CLUSTER(4)                                                                             \
    /* ---- p3: kh1, M-half0 + B-kh1 read ; stage (TAU+2) A-kh0 ---- */                         \
    _Pragma("unroll")                                                                           \
    for (int ii = 0; ii < 4; ++ii) af[ii] = *(const short8*)&a1k[addrA + ii * 512];             \
    _Pragma("unroll")                                                                           \
    for (int nf = 0; nf < 5; ++nf) bf[nf] = *(const short8*)&b1k[addrB + nf * 512];             \
    if (DO34) STAGE_A(A0s[cur_], ((TAU) + 2) * 64);                                             \
    LGKM0;                                                                                      \
    __builtin_amdgcn_s_barrier();                                                               \
    __builtin_amdgcn_sched_barrier(0);                                                          \
    MFMA_CLUSTER(0)                                                                             \
    /* ---- p4: kh1, M-half1 ; stage (TAU+2) B-kh0 ; vmcnt ---- */                              \
    _Pragma("unroll")                                                                           \
    for (int ii = 0; ii < 4; ++ii) af[ii] = *(const short8*)&a1k[addrA + (ii + 4) * 512];       \
    if (DO34) STAGE_B(B0s[cur_], ((TAU) + 2) * 64);                                             \
    LGKM0;                                                                                      \
    W4;                                                                                        \
    __builtin_amdgcn_s_barrier();                                                               \
    __builtin_amdgcn_sched_barrier(0);                                                          \
    MFMA_CLUSTER(4)                                                                             \
}

    #pragma unroll 2
    for (int tau = 0; tau < 14; ++tau)
        TILE_BODY(tau, 1, 1, VMW(8), VMW(8));
    TILE_BODY(14, 1, 0, VMW(8), VMW(4));
    TILE_BODY(15, 0, 0, VMW(0), ((void)0));

#undef TILE_BODY
#undef MFMA_CLUSTER
#undef STAGE_A
#undef STAGE_B

    // ---- epilogue: lane-local RoPE (+1/64 q-scale); V transposed ----
    const int cr = (lane >> 4) * 4;
    const int cc = lane & 15;
    const int rwbase = row0 + wm * 128;
    const float L2C = -0.41524101186092029f;  // -log2(10000)/32

    #pragma unroll
    for (int nf = 0; nf < 5; ++nf) {
        const int cg = col0 + wn * 80 + nf * 16;  // global col of this frag
        const int p  = cg >> 10;                  // 0=q 1=k 2=q2 3=k2 4=v
        const int h  = (cg >> 6) & 15;
        const int f  = (cg >> 4) & 3;
        if (p < 4) {
            const float sc  = (p == 0 || p == 2) ? 0.015625f : 1.0f;
            const float inv = exp2f((float)(f * 8 + (cc & 7)) * L2C);
            unsigned short* hp = Ch + (size_t)p * 4194304;
            #pragma unroll
            for (int ii = 0; ii < 8; ++ii) {
                int r0  = rwbase + ii * 16 + cr;
                int bhi = ((r0 >> 11) << 4) + h;
                size_t base = ((size_t)bhi * 2048 + (r0 & 2047)) * 64;
                #pragma unroll
                for (int rr = 0; rr < 4; ++rr) {
                    float tt = (float)((r0 + rr) & 2047);
                    float s0, c0;
                    __sincosf(tt * inv, &s0, &c0);
                    float x  = acc[ii][nf][rr];
                    float xp = __shfl_xor(x, 8, 64);
                    float y  = (cc < 8) ? (x * c0 + xp * s0) : (x * c0 - xp * s0);
                    hp[base + (size_t)rr * 64 + (f * 16 + cc)] = f2bf(y * sc);
                }
            }
        } else {
            #pragma unroll
            for (int ii = 0; ii < 8; ++ii) {
                int r0  = rwbase + ii * 16 + cr;
                int bhi = ((r0 >> 11) << 4) + h;
                int d   = f * 16 + cc;
                ushort4 o;
                o.x = f2bf(acc[ii][nf][0]); o.y = f2bf(acc[ii][nf][1]);
                o.z = f2bf(acc[ii][nf][2]); o.w = f2bf(acc[ii][nf][3]);
                *(ushort4*)(Vt + ((size_t)bhi * 64 + d) * 2048 + (r0 & 2047)) = o;
            }
        }
    }
}

// ---------------------------------------------------------------------------
// Output projection — 1-TERM bf16: C = Ah . Bh^T, fp32 out (UNCHANGED).
// 128x128 tile, grid (32,8) = 256 blocks = 1/CU, 4 waves (wave-tile 64x64),
// 16 MFMA : 8 ds_reads per K-step, 16 KB LDS, chunk-XOR swizzle, 2 barriers.
// ---------------------------------------------------------------------------
__global__ __launch_bounds__(256)
void gemm_proj(const unsigned short* __restrict__ Ap,
               const unsigned short* __restrict__ Bp,
               float* __restrict__ Cf)
{
    __shared__ __align__(16) unsigned short Ah[128 * 32];
    __shared__ __align__(16) unsigned short Bh[128 * 32];

    const int t    = threadIdx.x;
    const int lane = t & 63;
    const int s    = lane & 15;
    const int row0 = blockIdx.x * 128;
    const int col0 = blockIdx.y * 128;
    const int m0   = ((t >> 6) >> 1) * 64;
    const int n0   = ((t >> 6) & 1) * 64;

    floatx4 acc[4][4];
    #pragma unroll
    for (int i = 0; i < 4; ++i)
        #pragma unroll
        for (int j = 0; j < 4; ++j)
            acc[i][j] = (floatx4)(0.0f);

    const int sr  = t >> 2;
    const int skx = ((t & 3) ^ ((t >> 3) & 3)) * 8;
    char* dA  = (char*)Ah + (size_t)t * 16;
    char* dB  = (char*)Bh + (size_t)t * 16;
    const size_t arow = (size_t)(row0 + sr) * 2048 + skx;
    const size_t brow = (size_t)(col0 + sr) * 2048 + skx;

    #define ISSUE(k0)                                                                         \
    {                                                                                         \
        const unsigned short* ga = Ap + arow + (k0);                                          \
        const unsigned short* gb = Bp + brow + (k0);                                          \
        __builtin_amdgcn_global_load_lds((gvoid*)ga,                 (lvoid*)dA,          16, 0, 0); \
        __builtin_amdgcn_global_load_lds((gvoid*)(ga + 64*2048),     (lvoid*)(dA + 4096), 16, 0, 0); \
        __builtin_amdgcn_global_load_lds((gvoid*)gb,                 (lvoid*)dB,          16, 0, 0); \
        __builtin_amdgcn_global_load_lds((gvoid*)(gb + 64*2048),     (lvoid*)(dB + 4096), 16, 0, 0); \
    }

    const int cofs = (((lane >> 4) ^ ((lane >> 1) & 3)) << 3);

    ISSUE(0);
    for (int ks = 0; ks < 32; ++ks) {
        __syncthreads();
        short8 ahf[4], bhf[4];
        #pragma unroll
        for (int i = 0; i < 4; ++i)
            ahf[i] = *(const short8*)&Ah[(m0 + i * 16 + s) * 32 + cofs];
        #pragma unroll
        for (int j = 0; j < 4; ++j)
            bhf[j] = *(const short8*)&Bh[(n0 + j * 16 + s) * 32 + cofs];
        #pragma unroll
        for (int i = 0; i < 4; ++i)
            #pragma unroll
            for (int j = 0; j < 4; ++j)
                acc[i][j] = __builtin_amdgcn_mfma_f32_16x16x32_bf16(ahf[i], bhf[j], acc[i][j], 0, 0, 0);
        __syncthreads();
        if (ks + 1 < 32) ISSUE((ks + 1) * 32);
    }
    #undef ISSUE

    const int cr = (lane >> 4) * 4;
    const int cc = lane & 15;
    #pragma unroll
    for (int i = 0; i < 4; ++i)
        #pragma unroll
        for (int j = 0; j < 4; ++j) {
            int r = row0 + m0 + i * 16 + cr;
            int c = col0 + n0 + j * 16 + cc;
            #pragma unroll
            for (int rr = 0; rr < 4; ++rr)
                Cf[(size_t)(r + rr) * 1024 + c] = acc[i][j][rr];
        }
}

// ---------------------------------------------------------------------------
// MFMA bilinear causal attention — REVERTED to the round-12 version (best
// measured): 8-wave, balanced 2-pass (every block exactly 17 tile-iters,
// robust to ANY dispatch order — the round-13 one-tile-per-block split
// regressed because its balance depended on an unverified block->CU map),
// XCD-aware, T14 prefetch + double-buffered K/V, z single-bf16 epilogue.
// Grid 256 = 1 block/CU. LDS 128 KB.
// ---------------------------------------------------------------------------
__global__ __launch_bounds__(512, 2)
void attn_mfma(const unsigned short* __restrict__ qh, const unsigned short* __restrict__ q2h,
               const unsigned short* __restrict__ kh, const unsigned short* __restrict__ k2h,
               const unsigned short* __restrict__ vt, unsigned short* __restrict__ zout)
{
    __shared__ __align__(16) unsigned short smem[65536];   // 128 KB
    unsigned short* qs  = smem;              // [128][64] rot8 (init only)
    unsigned short* q2s = smem + 8192;
    unsigned short* psq = smem;              // [128][128] rot16, overlays qs/q2s
    unsigned short* kvb = smem + 16384;      // 2 x {ks 8192, k2s 8192, vts 8192}

    const int bid  = blockIdx.x;
    const int xcd  = bid & 7;
    const int slot = bid >> 3;          // 0..31
    const int hh   = slot >> 3;         // 0..3
    const int pr   = slot & 7;          // 0..7 (pair index)
    const int bh   = xcd * 4 + hh;
    const int t  = threadIdx.x;
    const int lane = t & 63;
    const int w    = t >> 6;          // 0..7
    const int s    = lane & 15;
    const int g    = lane >> 4;
    const int mk   = (w >> 1) * 32;   // 4-way k-split: 32 rows/wave
    const int nq   = (w & 1) * 64;    // 2-way q-split

    const int b = bh >> 4, h = bh & 15;

    short8 kf[2], k2f[2], vf[2];

#define LOADKV(TK) {                                                                \
    const unsigned short* kb  = kh  + ((size_t)bh * 2048 + (TK) * 128) * 64;        \
    const unsigned short* k2b = k2h + ((size_t)bh * 2048 + (TK) * 128) * 64;        \
    const unsigned short* vb  = vt  + (size_t)bh * 131072 + (TK) * 128;             \
    const int krow_ = t >> 2;                                                       \
    const int vd_   = t >> 3;                                                       \
    _Pragma("unroll")                                                               \
    for (int c = 0; c < 2; ++c) {                                                   \
        int cg_ = (t & 3) * 2 + c;                                                  \
        kf[c]  = *(const short8*)(kb  + (size_t)krow_ * 64 + cg_ * 8);              \
        k2f[c] = *(const short8*)(k2b + (size_t)krow_ * 64 + cg_ * 8);              \
        int cg16_ = (t & 7) * 2 + c;                                                \
        vf[c]  = *(const short8*)(vb + (size_t)vd_ * 2048 + cg16_ * 8);             \
    } }

#define WRITEKV(DST) {                                                              \
    unsigned short* ksd_  = (DST);                                                  \
    unsigned short* k2sd_ = (DST) + 8192;                                           \
    unsigned short* vtsd_ = (DST) + 16384;                                          \
    const int krow_ = t >> 2;                                                       \
    const int vd_   = t >> 3;                                                       \
    _Pragma("unroll")                                                               \
    for (int c = 0; c < 2; ++c) {                                                   \
        int cg_  = (t & 3) * 2 + c;                                                 \
        int cgm_ = (cg_ + krow_) & 7;                                               \
        *(short8*)&ksd_ [krow_ * 64 + cgm_ * 8] = kf[c];                            \
        *(short8*)&k2sd_[krow_ * 64 + cgm_ * 8] = k2f[c];                           \
        int cg16_  = (t & 7) * 2 + c;                                               \
        int cgm16_ = (cg16_ + vd_) & 15;                                            \
        *(short8*)&vtsd_[vd_ * 128 + cgm16_ * 8] = vf[c];                           \
    } }

    #pragma unroll
    for (int pass = 0; pass < 2; ++pass) {
        const int qt = pass ? pr : (15 - pr);

        __syncthreads();   // pass boundary: prev pass's psq/KV reads all done

        // issue K/V tile-0 loads early: latency overlaps q staging + hoist
        LOADKV(0);

        // ---- stage q, q2 for this q-tile ----
        {
            const unsigned short* qb  = qh  + ((size_t)bh * 2048 + qt * 128) * 64;
            const unsigned short* q2b = q2h + ((size_t)bh * 2048 + qt * 128) * 64;
            const int row = t >> 2;                    // 0..127
            #pragma unroll
            for (int c = 0; c < 2; ++c) {
                int cg  = (t & 3) * 2 + c;             // 0..7
                short8 a  = *(const short8*)(qb  + (size_t)row * 64 + cg * 8);
                short8 a2 = *(const short8*)(q2b + (size_t)row * 64 + cg * 8);
                int cgm = (cg + row) & 7;
                *(short8*)&qs [row * 64 + cgm * 8] = a;
                *(short8*)&q2s[row * 64 + cgm * 8] = a2;
            }
        }
        __syncthreads();   // qs visible
        short8 bq[2][4], bq2[2][4];
        #pragma unroll
        for (int kstep = 0; kstep < 2; ++kstep) {
            const int gl = kstep * 4 + g;
            #pragma unroll
            for (int j = 0; j < 4; ++j) {
                int row = nq + j * 16 + s;
                int a = row * 64 + ((gl + row) & 7) * 8;
                bq[kstep][j]  = *(const short8*)&qs [a];
                bq2[kstep][j] = *(const short8*)&q2s[a];
            }
        }

        // write KV[0] (compiler drains vmcnt for kf here), prefetch tile 1
        WRITEKV(kvb);
        if (qt > 0) LOADKV(1);
        __syncthreads();   // b_init: KV[0] visible; all waves' q-hoist done
                           // (guards psq overlay of qs)

        floatx4 zac[4];
        #pragma unroll
        for (int j = 0; j < 4; ++j)
            zac[j] = (floatx4)(0.0f);

        for (int tk = 0; tk <= qt; ++tk) {
            const int cur = tk & 1;
            unsigned short* kvc = kvb + cur * 24576;        // read buffer
            unsigned short* kvn = kvb + (cur ^ 1) * 24576;  // write buffer

            // ---- phase A: ds_write next K/V (overlaps S+P MFMA) ----
            if (tk < qt) WRITEKV(kvn);

            // ---- S + P, i-outer (2 frags of 16 k-rows per wave) ----
            #pragma unroll
            for (int i = 0; i < 2; ++i) {
                floatx4 a1[4], a2[4];
                #pragma unroll
                for (int j = 0; j < 4; ++j) { a1[j] = (floatx4)(0.0f); a2[j] = (floatx4)(0.0f); }
                #pragma unroll
                for (int kstep = 0; kstep < 2; ++kstep) {
                    const int gl = kstep * 4 + g;
                    int row = mk + i * 16 + s;
                    int a = row * 64 + ((gl + row) & 7) * 8;
                    short8 ak  = *(const short8*)&kvc[a];
                    short8 ak2 = *(const short8*)&kvc[8192 + a];
                    #pragma unroll
                    for (int j = 0; j < 4; ++j) {
                        a1[j] = __builtin_amdgcn_mfma_f32_16x16x32_bf16(ak,  bq[kstep][j],  a1[j], 0, 0, 0);
                        a2[j] = __builtin_amdgcn_mfma_f32_16x16x32_bf16(ak2, bq2[kstep][j], a2[j], 0, 0, 0);
                    }
                }
                // P-write for this i: psq region unread by anyone during the loop
                const int kl0   = mk + i * 16 + g * 4;
                const int chunk = kl0 >> 3;
                const int sub   = kl0 & 7;
                if (tk < qt) {
                    #pragma unroll
                    for (int j = 0; j < 4; ++j) {
                        const int ql = nq + j * 16 + s;
                        ushort4 pw;
                        pw.x = f2bf(a1[j][0] * a2[j][0]);
                        pw.y = f2bf(a1[j][1] * a2[j][1]);
                        pw.z = f2bf(a1[j][2] * a2[j][2]);
                        pw.w = f2bf(a1[j][3] * a2[j][3]);
                        *(ushort4*)&psq[ql * 128 + ((chunk + ql) & 15) * 8 + sub] = pw;
                    }
                } else {
                    #pragma unroll
                    for (int j = 0; j < 4; ++j) {
                        const int ql = nq + j * 16 + s;
                        ushort4 pw;
                        pw.x = (kl0 + 0 <= ql) ? f2bf(a1[j][0] * a2[j][0]) : (unsigned short)0;
                        pw.y = (kl0 + 1 <= ql) ? f2bf(a1[j][1] * a2[j][1]) : (unsigned short)0;
                        pw.z = (kl0 + 2 <= ql) ? f2bf(a1[j][2] * a2[j][2]) : (unsigned short)0;
                        pw.w = (kl0 + 3 <= ql) ? f2bf(a1[j][3] * a2[j][3]) : (unsigned short)0;
                        *(ushort4*)&psq[ql * 128 + ((chunk + ql) & 15) * 8 + sub] = pw;
                    }
                }
            }

            __syncthreads();   // b2: psq (and KV writes) visible

            // ---- phase B: prefetch K/V(tk+2) regs; latency hides under PV ----
            if (tk + 2 <= qt) LOADKV(tk + 2);
            __builtin_amdgcn_sched_barrier(0);

            // ---- PV: z[q][d] += P[q][k] * vT[d][k] ; wave owns 16 q-rows ----
            const int wm0 = w * 16;
            #pragma unroll
            for (int kstep = 0; kstep < 4; ++kstep) {
                const int cbase = kstep * 4 + g;
                short8 ap, bv[4];
                {
                    int q2_ = wm0 + s;
                    ap = *(const short8*)&psq[q2_ * 128 + ((cbase + q2_) & 15) * 8];
                }
                #pragma unroll
                for (int jd = 0; jd < 4; ++jd) {
                    int d = jd * 16 + s;
                    bv[jd] = *(const short8*)&kvc[16384 + d * 128 + ((cbase + d) & 15) * 8];
                }
                #pragma unroll
                for (int jd = 0; jd < 4; ++jd)
                    zac[jd] = __builtin_amdgcn_mfma_f32_16x16x32_bf16(ap, bv[jd], zac[jd], 0, 0, 0);
            }

            __syncthreads();   // bA: PV reads done; next iter may overwrite
                               // KV[cur] and psq
        }

        // ---- epilogue: z -> single bf16 into zout[4096][2048] (hi cols) ----
        const size_t zrow0 = (size_t)(b * TSEQ + qt * 128);
        #pragma unroll
        for (int j = 0; j < 4; ++j)
            #pragma unroll
            for (int r = 0; r < 4; ++r) {
                size_t row = zrow0 + w * 16 + g * 4 + r;
                int col = h * 64 + j * 16 + s;
                zout[row * 2048 + col] = f2bf(zac[j][r]);
            }
    }
#undef LOADKV
#undef WRITEKV
}

// ---------------------------------------------------------------------------
extern "C" void kernel_launch(void* const* d_in, const int* in_sizes, int n_in,
                              void* d_out, int out_size, void* d_ws, size_t ws_size,
                              hipStream_t stream)
{
    const float* x     = (const float*)d_in[0];
    const float* Wq    = (const float*)d_in[1];
    const float* Wk    = (const float*)d_in[2];
    const float* Wq2   = (const float*)d_in[3];
    const float* Wk2   = (const float*)d_in[4];
    const float* Wv    = (const float*)d_in[5];
    const float* Wproj = (const float*)d_in[6];

    // workspace (bytes):
    //   Xp    bf16 [4096][2048] (x-hi, later z single-bf16) @ 0       (16,777,216)
    //   Wp    bf16 [6144][2048]                          @ 16,777,216 (25,165,824)
    //         rows [0,1024)    = Wproj [hi|dead]
    //         rows [1024,6144) = Wq,Wk,Wq2,Wk2 (head-interleaved), Wv [hi|dead]
    //   heads bf16 4x[32][2048][64] (q,k,q2,k2)          @ 41,943,040 (33,554,432)
    //   vt    bf16 [32][64][2048]                        @ 75,497,472 ( 8,388,608)
    unsigned short* Xp    = (unsigned short*)d_ws;
    unsigned short* Wp    = (unsigned short*)((char*)d_ws + 16777216);
    unsigned short* heads = (unsigned short*)((char*)d_ws + 41943040);
    unsigned short* vt    = (unsigned short*)((char*)d_ws + 75497472);

    const size_t HS = (size_t)32 * 2048 * 64;
    unsigned short* qh  = heads;
    unsigned short* kh  = heads + 1 * HS;
    unsigned short* q2h = heads + 2 * HS;
    unsigned short* k2h = heads + 3 * HS;

    pack_all_kernel<<<10240, 256, 0, stream>>>(x, Wproj, Wq, Wk, Wq2, Wk2, Wv, Xp, Wp);
    gemm_qkv<<<256, 512, 0, stream>>>(Xp, Wp + (size_t)1024 * 2048, heads, vt);
    attn_mfma<<<256, 512, 0, stream>>>(qh, q2h, kh, k2h, vt, Xp);
    gemm_proj<<<dim3(32, 8), 256, 0, stream>>>(Xp, Wp, (float*)d_out);
}